// Round 8
// baseline (1392.303 us; speedup 1.0000x reference)
//
#include <hip/hip_runtime.h>
#include <hip/hip_bf16.h>

typedef int  i32x4 __attribute__((ext_vector_type(4)));

// ---------------------------------------------------------------------------
// Prep 1: x fp32 -> int8 (per-row symmetric quant), rowsum folded to fp32.
// ---------------------------------------------------------------------------
__global__ __launch_bounds__(256) void prep_x_i8(const float* __restrict__ x,
                                                 int* __restrict__ xq,
                                                 float* __restrict__ rsum,
                                                 float* __restrict__ rscale,
                                                 int K) {
    const int row = blockIdx.x;
    const float* xr = x + (size_t)row * K;
    __shared__ float xs[4096];
    float mx = 0.f;
    for (int c = threadIdx.x * 4; c < K; c += blockDim.x * 4) {
        float4 v = *reinterpret_cast<const float4*>(xr + c);
        *reinterpret_cast<float4*>(xs + c) = v;
        mx = fmaxf(mx, fmaxf(fmaxf(fabsf(v.x), fabsf(v.y)),
                             fmaxf(fabsf(v.z), fabsf(v.w))));
    }
    #pragma unroll
    for (int off = 32; off > 0; off >>= 1) mx = fmaxf(mx, __shfl_down(mx, off));
    __shared__ float wmax[4];
    __shared__ float s_sx, s_inv;
    const int lane = threadIdx.x & 63, wv = threadIdx.x >> 6;
    if (lane == 0) wmax[wv] = mx;
    __syncthreads();
    if (threadIdx.x == 0) {
        float m = fmaxf(fmaxf(wmax[0], wmax[1]), fmaxf(wmax[2], wmax[3]));
        m = fmaxf(m, 1e-20f);
        s_sx = m / 127.f; s_inv = 127.f / m;
    }
    __syncthreads();
    const float inv = s_inv;
    int qs = 0;
    for (int c = threadIdx.x * 4; c < K; c += blockDim.x * 4) {
        float4 v = *reinterpret_cast<const float4*>(xs + c);
        const int q0 = __float2int_rn(v.x * inv), q1 = __float2int_rn(v.y * inv);
        const int q2 = __float2int_rn(v.z * inv), q3 = __float2int_rn(v.w * inv);
        qs += q0 + q1 + q2 + q3;
        const unsigned p = (unsigned)(q0 & 255) | ((unsigned)(q1 & 255) << 8) |
                           ((unsigned)(q2 & 255) << 16) | ((unsigned)(q3 & 255) << 24);
        xq[((size_t)row * K + c) >> 2] = (int)p;
    }
    #pragma unroll
    for (int off = 32; off > 0; off >>= 1) qs += __shfl_down(qs, off);
    __shared__ int wqs[4];
    if (lane == 0) wqs[wv] = qs;
    __syncthreads();
    if (threadIdx.x == 0) {
        const int t = wqs[0] + wqs[1] + wqs[2] + wqs[3];
        rsum[row] = s_sx * (float)t;
        rscale[row] = s_sx;
    }
}

// ---------------------------------------------------------------------------
// Prep 2: weight int32 codes -> int8 bytes. 16 codes / thread, 16B writes.
// ---------------------------------------------------------------------------
__global__ __launch_bounds__(256) void prep_w_i8(const int* __restrict__ w,
                                                 int* __restrict__ wq) {
    const size_t i = (size_t)blockIdx.x * blockDim.x + threadIdx.x;
    const int4* src = reinterpret_cast<const int4*>(w) + i * 4;
    int4 a = src[0], b = src[1], c = src[2], d = src[3];
    int4 o;
    o.x = (a.x & 255) | ((a.y & 255) << 8) | ((a.z & 255) << 16) | ((a.w & 255) << 24);
    o.y = (b.x & 255) | ((b.y & 255) << 8) | ((b.z & 255) << 16) | ((b.w & 255) << 24);
    o.z = (c.x & 255) | ((c.y & 255) << 8) | ((c.z & 255) << 16) | ((c.w & 255) << 24);
    o.w = (d.x & 255) | ((d.y & 255) << 8) | ((d.z & 255) << 16) | ((d.w & 255) << 24);
    reinterpret_cast<int4*>(wq)[i] = o;
}

// ---------------------------------------------------------------------------
// 256x256 int8 GEMM, ring-2 of K=64 slabs (64 KiB LDS -> 2 blocks/CU,
// 16 waves/CU). One phase per slab: 12 ds_read_b128 | stage next slab
// (4 gloads) | lgkmcnt(0) | 32 MFMA | vmcnt(0) | barrier.
// Cross-block TLP covers the per-phase drain (thesis: 2 independent
// barrier domains per CU fill each other's LDS/drain bubbles).
// Hazards: stage(s+1)->slot q is write-safe (slab s-1 reads in q were
// lgkm(0)-proven before phase s-1's barrier); reads of slot p are
// vmcnt(0)+barrier-proven by phase s-1. Same swizzle/layout as R4.
// out[m,o] = sc[o]*(sx[m]*dot_i32[m,o] - zp[o]*rsum[m]) + bias[o]
// ---------------------------------------------------------------------------
__device__ __forceinline__ void async16(void* lds, const void* g) {
    __builtin_amdgcn_global_load_lds(
        (const __attribute__((address_space(1))) unsigned*)g,
        (__attribute__((address_space(3))) unsigned*)lds, 16, 0, 0);
}

__global__ __launch_bounds__(512, 4) void qgemm2i(
    const char* __restrict__ A, const char* __restrict__ B,
    const float* __restrict__ rsum, const float* __restrict__ rscale,
    const float* __restrict__ scale, const float* __restrict__ zp,
    const float* __restrict__ bias, float* __restrict__ C,
    int M, int N, int K) {
    extern __shared__ char smem[];
    char* const AsR = smem;            // 2 x 16 KiB A slabs
    char* const BsR = smem + 32768;    // 2 x 16 KiB B slabs

    const int tid  = threadIdx.x;
    const int lane = tid & 63;
    const int wid  = tid >> 6;
    const int wm = wid >> 2, wn = wid & 3;   // 2 x 4 waves, wave tile 128x64
    const int l15 = lane & 15;

    // bijective XCD swizzle (gridDim.x % 8 == 0)
    const int nbn = N >> 8;
    int wg = blockIdx.x;
    wg = (wg & 7) * (gridDim.x >> 3) + (wg >> 3);
    const int bm = wg / nbn, bn = wg % nbn;

    // per-thread staging source offsets (inverse-swizzled global address)
    const int r0s = tid >> 2, sls = tid & 3;
    size_t a_src[2], b_src[2];
    int lds_off[2];
    #pragma unroll
    for (int j = 0; j < 2; ++j) {
        const int row = r0s + j * 128;
        const int sl  = sls ^ ((row >> 1) & 3);
        a_src[j] = ((size_t)(bm * 256 + row)) * K + sl * 16;
        b_src[j] = ((size_t)(bn * 256 + row)) * K + sl * 16;
        lds_off[j] = (j * 512 + tid) * 16;
    }

    // stage slab u (K-slice u*64) into ring slot sl: A 2 gloads + B 2 gloads
    auto STAGE = [&](int u, int sl) {
        const int kc = u * 64;
        char* const da = AsR + sl * 16384;
        char* const db = BsR + sl * 16384;
        #pragma unroll
        for (int j = 0; j < 2; ++j) async16(da + lds_off[j], A + a_src[j] + kc);
        #pragma unroll
        for (int j = 0; j < 2; ++j) async16(db + lds_off[j], B + b_src[j] + kc);
    };

    // fragment-read constants (swizzled ds_read address)
    const int sw16 = (((lane >> 4) ^ ((lane >> 1) & 3)) << 4);
    const int a_ro = (wm * 128 + l15) * 64 + sw16;   // + mf*1024, mf 0..7
    const int b_ro = (wn * 64 + l15) * 64 + sw16;    // + nf*1024, nf 0..3

    i32x4 acc[8][4] = {};

    const int NS = K >> 6;     // 64 slabs

    // ---- prologue: stage slab 0 into slot 0, prove, barrier ----
    STAGE(0, 0);
    asm volatile("s_waitcnt vmcnt(0)" ::: "memory");
    asm volatile("s_barrier" ::: "memory");

    #pragma unroll 1
    for (int s = 0; s < NS; ++s) {
        const int p = s & 1, q = p ^ 1;
        const char* ha = AsR + p * 16384;
        const char* hb = BsR + p * 16384;

        i32x4 af[8], bf[4];
        #pragma unroll
        for (int m = 0; m < 8; ++m)
            af[m] = *(const i32x4*)(ha + a_ro + m * 1024);
        #pragma unroll
        for (int n = 0; n < 4; ++n)
            bf[n] = *(const i32x4*)(hb + b_ro + n * 1024);

        int u = s + 1; if (u >= NS) u = NS - 1;   // clamped dummy prefetch
        STAGE(u, q);

        asm volatile("s_waitcnt lgkmcnt(0)" ::: "memory");
        __builtin_amdgcn_sched_barrier(0);
        __builtin_amdgcn_s_setprio(1);
        #pragma unroll
        for (int m = 0; m < 8; ++m)
            #pragma unroll
            for (int n = 0; n < 4; ++n)
                acc[m][n] = __builtin_amdgcn_mfma_i32_16x16x64_i8(
                    af[m], bf[n], acc[m][n], 0, 0, 0);
        __builtin_amdgcn_s_setprio(0);
        __builtin_amdgcn_sched_barrier(0);
        asm volatile("s_waitcnt vmcnt(0)" ::: "memory");
        asm volatile("s_barrier" ::: "memory");
    }

    // ---- epilogue: dequant. D: col=lane&15, row=4*(lane>>4)+i ----
    float sc[4], zz[4], bb[4];
    #pragma unroll
    for (int n = 0; n < 4; ++n) {
        const int o = bn * 256 + wn * 64 + n * 16 + l15;
        sc[n] = scale[o]; zz[n] = zp[o]; bb[n] = bias[o];
    }
    const int hi4 = (lane >> 4) << 2;
    #pragma unroll
    for (int mf = 0; mf < 8; ++mf) {
        const int r0 = bm * 256 + wm * 128 + mf * 16 + hi4;
        float rs[4], sx[4];
        #pragma unroll
        for (int i = 0; i < 4; ++i) { rs[i] = rsum[r0 + i]; sx[i] = rscale[r0 + i]; }
        #pragma unroll
        for (int n = 0; n < 4; ++n) {
            const int o = bn * 256 + wn * 64 + n * 16 + l15;
            #pragma unroll
            for (int i = 0; i < 4; ++i)
                C[(size_t)(r0 + i) * N + o] =
                    sc[n] * (sx[i] * (float)acc[mf][n][i] - zz[n] * rs[i]) + bb[n];
        }
    }
}

// ---------------------------------------------------------------------------
extern "C" void kernel_launch(void* const* d_in, const int* in_sizes, int n_in,
                              void* d_out, int out_size, void* d_ws, size_t ws_size,
                              hipStream_t stream) {
    const float* x     = (const float*)d_in[0];
    const int*   w     = (const int*)d_in[1];
    const float* scale = (const float*)d_in[2];
    const float* zp    = (const float*)d_in[3];
    const float* bias  = (const float*)d_in[4];
    float* out = (float*)d_out;

    const int N = in_sizes[2];              // D_OUT = 4096
    const int K = in_sizes[1] / N;          // D_IN  = 4096
    const int M = in_sizes[0] / K;          // B*S   = 8192

    char*  xq  = (char*)d_ws;                                   // M*K bytes
    char*  wq  = (char*)d_ws + (size_t)M * K;                   // N*K bytes
    float* rs  = (float*)((char*)d_ws + (size_t)M * K + (size_t)N * K);
    float* rsc = rs + M;

    prep_x_i8<<<M, 256, 0, stream>>>(x, (int*)xq, rs, rsc, K);
    prep_w_i8<<<(int)(((size_t)N * K / 16) / 256), 256, 0, stream>>>(w, (int*)wq);

    (void)hipFuncSetAttribute((const void*)qgemm2i,
                              hipFuncAttributeMaxDynamicSharedMemorySize, 65536);
    const int nwg = (M / 256) * (N / 256);   // 512, % 8 == 0
    qgemm2i<<<nwg, 512, 65536, stream>>>(xq, wq, rs, rsc, scale, zp, bias,
                                         out, M, N, K);
}

// Round 10
// 179.053 us; speedup vs baseline: 7.7759x; 7.7759x over previous
//
#include <hip/hip_runtime.h>
#include <hip/hip_bf16.h>

typedef int  i32x4 __attribute__((ext_vector_type(4)));

// ---------------------------------------------------------------------------
// Fused prep: blocks [0, M) quantize x rows (fp32 -> int8 per-row symmetric,
// rowsum folded to fp32); blocks [M, M + N*K/4096) pack weight int32 codes
// into int8 bytes. Both phases are BW-bound; fusing overlaps them and saves
// a launch gap. Disjoint outputs; block-level branch (no divergence).
// ---------------------------------------------------------------------------
__global__ __launch_bounds__(256) void prep_fused(const float* __restrict__ x,
                                                  const int* __restrict__ w,
                                                  int* __restrict__ xq,
                                                  int* __restrict__ wq,
                                                  float* __restrict__ rsum,
                                                  float* __restrict__ rscale,
                                                  int M, int K) {
    if ((int)blockIdx.x >= M) {
        // ---- weight pack: 16 codes / thread, 16B writes ----
        const size_t i = (size_t)(blockIdx.x - M) * blockDim.x + threadIdx.x;
        const int4* src = reinterpret_cast<const int4*>(w) + i * 4;
        int4 a = src[0], b = src[1], c = src[2], d = src[3];
        int4 o;
        o.x = (a.x & 255) | ((a.y & 255) << 8) | ((a.z & 255) << 16) | ((a.w & 255) << 24);
        o.y = (b.x & 255) | ((b.y & 255) << 8) | ((b.z & 255) << 16) | ((b.w & 255) << 24);
        o.z = (c.x & 255) | ((c.y & 255) << 8) | ((c.z & 255) << 16) | ((c.w & 255) << 24);
        o.w = (d.x & 255) | ((d.y & 255) << 8) | ((d.z & 255) << 16) | ((d.w & 255) << 24);
        reinterpret_cast<int4*>(wq)[i] = o;
        return;
    }
    // ---- x row quantize ----
    const int row = blockIdx.x;
    const float* xr = x + (size_t)row * K;
    __shared__ float xs[4096];
    float mx = 0.f;
    for (int c = threadIdx.x * 4; c < K; c += blockDim.x * 4) {
        float4 v = *reinterpret_cast<const float4*>(xr + c);
        *reinterpret_cast<float4*>(xs + c) = v;
        mx = fmaxf(mx, fmaxf(fmaxf(fabsf(v.x), fabsf(v.y)),
                             fmaxf(fabsf(v.z), fabsf(v.w))));
    }
    #pragma unroll
    for (int off = 32; off > 0; off >>= 1) mx = fmaxf(mx, __shfl_down(mx, off));
    __shared__ float wmax[4];
    __shared__ float s_sx, s_inv;
    const int lane = threadIdx.x & 63, wv = threadIdx.x >> 6;
    if (lane == 0) wmax[wv] = mx;
    __syncthreads();
    if (threadIdx.x == 0) {
        float m = fmaxf(fmaxf(wmax[0], wmax[1]), fmaxf(wmax[2], wmax[3]));
        m = fmaxf(m, 1e-20f);
        s_sx = m / 127.f; s_inv = 127.f / m;
    }
    __syncthreads();
    const float inv = s_inv;
    int qs = 0;
    for (int c = threadIdx.x * 4; c < K; c += blockDim.x * 4) {
        float4 v = *reinterpret_cast<const float4*>(xs + c);
        const int q0 = __float2int_rn(v.x * inv), q1 = __float2int_rn(v.y * inv);
        const int q2 = __float2int_rn(v.z * inv), q3 = __float2int_rn(v.w * inv);
        qs += q0 + q1 + q2 + q3;
        const unsigned p = (unsigned)(q0 & 255) | ((unsigned)(q1 & 255) << 8) |
                           ((unsigned)(q2 & 255) << 16) | ((unsigned)(q3 & 255) << 24);
        xq[((size_t)row * K + c) >> 2] = (int)p;
    }
    #pragma unroll
    for (int off = 32; off > 0; off >>= 1) qs += __shfl_down(qs, off);
    __shared__ int wqs[4];
    if (lane == 0) wqs[wv] = qs;
    __syncthreads();
    if (threadIdx.x == 0) {
        const int t = wqs[0] + wqs[1] + wqs[2] + wqs[3];
        rsum[row] = s_sx * (float)t;
        rscale[row] = s_sx;
    }
}

// ---------------------------------------------------------------------------
// 8-phase 256x256 int8 GEMM (verified passing in R5 at 137 us; byte-identical
// K-loop). Double-buffered 2x(K=128) tiles, counted-lgkm fragment pipeline
// (1 phase ahead), vmcnt(8) at even phases. MFMA i32_16x16x64_i8.
// out[m,o] = sc[o]*(sx[m]*dot_i32[m,o] - zp[o]*rsum[m]) + bias[o]
// A: M x K i8 row-major; B: N x K i8 row-major (B^T GEMM).
// LDS unit = 256 rows x 64 B (one K=64 slab) = 16 KiB; 4 A units + 4 B units.
// Swizzle: 16B slot within a row's 64B: phys = log ^ ((row>>1)&3); staged
// linearly via global_load_lds from inverse-swizzled global source.
// ---------------------------------------------------------------------------
__device__ __forceinline__ void async16(void* lds, const void* g) {
    __builtin_amdgcn_global_load_lds(
        (const __attribute__((address_space(1))) unsigned*)g,
        (__attribute__((address_space(3))) unsigned*)lds, 16, 0, 0);
}

__global__ __launch_bounds__(512, 2) void qgemm8i(
    const char* __restrict__ A, const char* __restrict__ B,
    const float* __restrict__ rsum, const float* __restrict__ rscale,
    const float* __restrict__ scale, const float* __restrict__ zp,
    const float* __restrict__ bias, float* __restrict__ C,
    int M, int N, int K) {
    extern __shared__ char smem[];
    char* const AsB = smem;            // 4 x 16 KiB A units
    char* const BsB = smem + 65536;    // 4 x 16 KiB B units

    const int tid  = threadIdx.x;
    const int lane = tid & 63;
    const int wid  = tid >> 6;
    const int wm = wid >> 2, wn = wid & 3;   // 2 x 4 waves
    const int l15 = lane & 15;

    // bijective XCD swizzle (gridDim.x % 8 == 0)
    const int nbn = N >> 8;
    int wg = blockIdx.x;
    wg = (wg & 7) * (gridDim.x >> 3) + (wg >> 3);
    const int bm = wg / nbn, bn = wg % nbn;

    // per-thread staging source offsets (inverse-swizzled global address)
    const int r0s = tid >> 2, sls = tid & 3;
    size_t a_src[2], b_src[2];
    int lds_off[2];
    #pragma unroll
    for (int j = 0; j < 2; ++j) {
        const int row = r0s + j * 128;
        const int sl  = sls ^ ((row >> 1) & 3);
        a_src[j] = ((size_t)(bm * 256 + row)) * K + sl * 16;
        b_src[j] = ((size_t)(bn * 256 + row)) * K + sl * 16;
        lds_off[j] = (j * 512 + tid) * 16;
    }

    auto stageA = [&](int u, int ks, int buf) {
        const int kc = u * 128 + ks * 64;     // byte offset along K
        char* const dst = AsB + (buf * 2 + ks) * 16384;
        #pragma unroll
        for (int j = 0; j < 2; ++j) async16(dst + lds_off[j], A + a_src[j] + kc);
    };
    auto stageB = [&](int u, int ks, int buf) {
        const int kc = u * 128 + ks * 64;
        char* const dst = BsB + (buf * 2 + ks) * 16384;
        #pragma unroll
        for (int j = 0; j < 2; ++j) async16(dst + lds_off[j], B + b_src[j] + kc);
    };

    // fragment-read constants (swizzled ds_read address)
    const int sw16 = (((lane >> 4) ^ ((lane >> 1) & 3)) << 4);
    const int a_ro = (wm * 128 + l15) * 64 + sw16;   // + mf*1024
    const int b_ro = (wn * 64 + l15) * 64 + sw16;    // + nf*1024

    i32x4 acc[8][4] = {};
    i32x4 af0[4], af1[4], bfr0[4], bfr1[4];

    const int NT  = K >> 7;    // K/128 tiles = 32
    const int NIT = NT >> 1;   // 2 tiles / iteration

#define READ_AF(DST, BUF, KS, QM)                                              \
    {                                                                          \
        const char* _ha = AsB + ((BUF) * 2 + (KS)) * 16384;                    \
        _Pragma("unroll")                                                      \
        for (int m = 0; m < 4; ++m)                                            \
            DST[m] = *(const i32x4*)(_ha + a_ro + ((QM) * 4 + m) * 1024);      \
    }

#define READ_BF(DST, BUF, KS)                                                  \
    {                                                                          \
        const char* _hb = BsB + ((BUF) * 2 + (KS)) * 16384;                    \
        _Pragma("unroll")                                                      \
        for (int n = 0; n < 4; ++n)                                            \
            DST[n] = *(const i32x4*)(_hb + b_ro + n * 1024);                   \
    }

#define MFMA16(QM, AF, BF)                                                     \
    __builtin_amdgcn_s_setprio(1);                                             \
    _Pragma("unroll")                                                          \
    for (int m = 0; m < 4; ++m)                                                \
        _Pragma("unroll")                                                      \
        for (int n = 0; n < 4; ++n)                                            \
            acc[(QM) * 4 + m][n] = __builtin_amdgcn_mfma_i32_16x16x64_i8(      \
                AF[m], BF[n], acc[(QM) * 4 + m][n], 0, 0, 0);                  \
    __builtin_amdgcn_s_setprio(0);

#define LGKM(N) asm volatile("s_waitcnt lgkmcnt(" #N ")" ::: "memory");        \
                __builtin_amdgcn_sched_barrier(0);
#define ENDPH   __builtin_amdgcn_sched_barrier(0);                             \
                asm volatile("s_barrier" ::: "memory");
#define VM8     asm volatile("s_waitcnt vmcnt(8)" ::: "memory");

    // ---- prologue: tile0 {B0,A0,B1,A1}; tile1 {B0,A0,B1} stays in flight ----
    stageB(0, 0, 0); stageA(0, 0, 0); stageB(0, 1, 0); stageA(0, 1, 0);
    asm volatile("s_waitcnt vmcnt(4)" ::: "memory");
    stageB(1, 0, 1); stageA(1, 0, 1); stageB(1, 1, 1);
    asm volatile("s_waitcnt vmcnt(6)" ::: "memory");
    asm volatile("s_barrier" ::: "memory");
    READ_AF(af1, 0, 0, 0);
    READ_BF(bfr0, 0, 0);

    #pragma unroll 1
    for (int i = 0; i < NIT; ++i) {
        const int t  = 2 * i;
        const int u1 = t + 1;
        int u2 = t + 2; if (u2 >= NT) u2 = NT - 1;   // clamped dummy prefetch
        int u3 = t + 3; if (u3 >= NT) u3 = NT - 1;   // (keeps vmcnt bookkeeping)

        // ph1: MFMA t:KS0:QM0 | prefetch (t:KS0 QM1 af) | stage A(t+1,1)
        READ_AF(af0, 0, 0, 1);
        stageA(u1, 1, 1);
        LGKM(4)
        MFMA16(0, af1, bfr0);
        ENDPH
        // ph2: MFMA t:KS0:QM1 | prefetch (t:KS1 af+bf) | stage B(t+2,0)
        VM8
        READ_AF(af1, 0, 1, 0);
        READ_BF(bfr1, 0, 1);
        stageB(u2, 0, 0);
        LGKM(8)
        MFMA16(1, af0, bfr0);
        ENDPH
        // ph3: MFMA t:KS1:QM0 | prefetch (t:KS1 QM1 af) | stage A(t+2,0)
        READ_AF(af0, 0, 1, 1);
        stageA(u2, 0, 0);
        LGKM(4)
        MFMA16(0, af1, bfr1);
        ENDPH
        // ph4: MFMA t:KS1:QM1 | prefetch (t+1:KS0 af+bf) | stage B(t+2,1)
        VM8
        READ_AF(af1, 1, 0, 0);
        READ_BF(bfr0, 1, 0);
        stageB(u2, 1, 0);
        LGKM(8)
        MFMA16(1, af0, bfr1);
        ENDPH
        // ph5: MFMA t+1:KS0:QM0 | prefetch (t+1:KS0 QM1 af) | stage A(t+2,1)
        READ_AF(af0, 1, 0, 1);
        stageA(u2, 1, 0);
        LGKM(4)
        MFMA16(0, af1, bfr0);
        ENDPH
        // ph6: MFMA t+1:KS0:QM1 | prefetch (t+1:KS1 af+bf) | stage B(t+3,0)
        VM8
        READ_AF(af1, 1, 1, 0);
        READ_BF(bfr1, 1, 1);
        stageB(u3, 0, 1);
        LGKM(8)
        MFMA16(1, af0, bfr0);
        ENDPH
        // ph7: MFMA t+1:KS1:QM0 | prefetch (t+1:KS1 QM1 af) | stage A(t+3,0)
        READ_AF(af0, 1, 1, 1);
        stageA(u3, 0, 1);
        LGKM(4)
        MFMA16(0, af1, bfr1);
        ENDPH
        // ph8: MFMA t+1:KS1:QM1 | prefetch (t+2:KS0 af+bf) | stage B(t+3,1)
        VM8
        READ_AF(af1, 0, 0, 0);
        READ_BF(bfr0, 0, 0);
        stageB(u3, 1, 1);
        LGKM(8)
        MFMA16(1, af0, bfr1);
        ENDPH
    }
#undef READ_AF
#undef READ_BF
#undef MFMA16
#undef LGKM
#undef ENDPH
#undef VM8

    // ---- epilogue: dequant. D: col=lane&15, row=4*(lane>>4)+i ----
    float sc[4], zz[4], bb[4];
    #pragma unroll
    for (int n = 0; n < 4; ++n) {
        const int o = bn * 256 + wn * 64 + n * 16 + l15;
        sc[n] = scale[o]; zz[n] = zp[o]; bb[n] = bias[o];
    }
    const int hi4 = (lane >> 4) << 2;
    #pragma unroll
    for (int mf = 0; mf < 8; ++mf) {
        const int r0 = bm * 256 + wm * 128 + mf * 16 + hi4;
        float rs[4], sx[4];
        #pragma unroll
        for (int i = 0; i < 4; ++i) { rs[i] = rsum[r0 + i]; sx[i] = rscale[r0 + i]; }
        #pragma unroll
        for (int n = 0; n < 4; ++n) {
            const int o = bn * 256 + wn * 64 + n * 16 + l15;
            #pragma unroll
            for (int i = 0; i < 4; ++i)
                C[(size_t)(r0 + i) * N + o] =
                    sc[n] * (sx[i] * (float)acc[mf][n][i] - zz[n] * rs[i]) + bb[n];
        }
    }
}

// ---------------------------------------------------------------------------
extern "C" void kernel_launch(void* const* d_in, const int* in_sizes, int n_in,
                              void* d_out, int out_size, void* d_ws, size_t ws_size,
                              hipStream_t stream) {
    const float* x     = (const float*)d_in[0];
    const int*   w     = (const int*)d_in[1];
    const float* scale = (const float*)d_in[2];
    const float* zp    = (const float*)d_in[3];
    const float* bias  = (const float*)d_in[4];
    float* out = (float*)d_out;

    const int N = in_sizes[2];              // D_OUT = 4096
    const int K = in_sizes[1] / N;          // D_IN  = 4096
    const int M = in_sizes[0] / K;          // B*S   = 8192

    char*  xq  = (char*)d_ws;                                   // M*K bytes
    char*  wq  = (char*)d_ws + (size_t)M * K;                   // N*K bytes
    float* rs  = (float*)((char*)d_ws + (size_t)M * K + (size_t)N * K);
    float* rsc = rs + M;

    const int wblocks = (int)(((size_t)N * K / 16) / 256);      // 4096
    prep_fused<<<M + wblocks, 256, 0, stream>>>(x, w, (int*)xq, (int*)wq,
                                                rs, rsc, M, K);

    (void)hipFuncSetAttribute((const void*)qgemm8i,
                              hipFuncAttributeMaxDynamicSharedMemorySize, 131072);
    const int nwg = (M / 256) * (N / 256);   // 512, % 8 == 0
    qgemm8i<<<nwg, 512, 131072, stream>>>(xq, wq, rs, rsc, scale, zp, bias,
                                          out, M, N, K);
}

// Round 11
// 178.470 us; speedup vs baseline: 7.8013x; 1.0033x over previous
//
#include <hip/hip_runtime.h>
#include <hip/hip_bf16.h>

typedef int  i32x4 __attribute__((ext_vector_type(4)));

// ---------------------------------------------------------------------------
// Fused prep: blocks [0, M) quantize x rows (fp32 -> int8 per-row symmetric,
// rowsum folded to fp32); blocks [M, ...) pack weight int32 codes to int8.
// ---------------------------------------------------------------------------
__global__ __launch_bounds__(256) void prep_fused(const float* __restrict__ x,
                                                  const int* __restrict__ w,
                                                  int* __restrict__ xq,
                                                  int* __restrict__ wq,
                                                  float* __restrict__ rsum,
                                                  float* __restrict__ rscale,
                                                  int M, int K) {
    if ((int)blockIdx.x >= M) {
        const size_t i = (size_t)(blockIdx.x - M) * blockDim.x + threadIdx.x;
        const int4* src = reinterpret_cast<const int4*>(w) + i * 4;
        int4 a = src[0], b = src[1], c = src[2], d = src[3];
        int4 o;
        o.x = (a.x & 255) | ((a.y & 255) << 8) | ((a.z & 255) << 16) | ((a.w & 255) << 24);
        o.y = (b.x & 255) | ((b.y & 255) << 8) | ((b.z & 255) << 16) | ((b.w & 255) << 24);
        o.z = (c.x & 255) | ((c.y & 255) << 8) | ((c.z & 255) << 16) | ((c.w & 255) << 24);
        o.w = (d.x & 255) | ((d.y & 255) << 8) | ((d.z & 255) << 16) | ((d.w & 255) << 24);
        reinterpret_cast<int4*>(wq)[i] = o;
        return;
    }
    const int row = blockIdx.x;
    const float* xr = x + (size_t)row * K;
    __shared__ float xs[4096];
    float mx = 0.f;
    for (int c = threadIdx.x * 4; c < K; c += blockDim.x * 4) {
        float4 v = *reinterpret_cast<const float4*>(xr + c);
        *reinterpret_cast<float4*>(xs + c) = v;
        mx = fmaxf(mx, fmaxf(fmaxf(fabsf(v.x), fabsf(v.y)),
                             fmaxf(fabsf(v.z), fabsf(v.w))));
    }
    #pragma unroll
    for (int off = 32; off > 0; off >>= 1) mx = fmaxf(mx, __shfl_down(mx, off));
    __shared__ float wmax[4];
    __shared__ float s_sx, s_inv;
    const int lane = threadIdx.x & 63, wv = threadIdx.x >> 6;
    if (lane == 0) wmax[wv] = mx;
    __syncthreads();
    if (threadIdx.x == 0) {
        float m = fmaxf(fmaxf(wmax[0], wmax[1]), fmaxf(wmax[2], wmax[3]));
        m = fmaxf(m, 1e-20f);
        s_sx = m / 127.f; s_inv = 127.f / m;
    }
    __syncthreads();
    const float inv = s_inv;
    int qs = 0;
    for (int c = threadIdx.x * 4; c < K; c += blockDim.x * 4) {
        float4 v = *reinterpret_cast<const float4*>(xs + c);
        const int q0 = __float2int_rn(v.x * inv), q1 = __float2int_rn(v.y * inv);
        const int q2 = __float2int_rn(v.z * inv), q3 = __float2int_rn(v.w * inv);
        qs += q0 + q1 + q2 + q3;
        const unsigned p = (unsigned)(q0 & 255) | ((unsigned)(q1 & 255) << 8) |
                           ((unsigned)(q2 & 255) << 16) | ((unsigned)(q3 & 255) << 24);
        xq[((size_t)row * K + c) >> 2] = (int)p;
    }
    #pragma unroll
    for (int off = 32; off > 0; off >>= 1) qs += __shfl_down(qs, off);
    __shared__ int wqs[4];
    if (lane == 0) wqs[wv] = qs;
    __syncthreads();
    if (threadIdx.x == 0) {
        const int t = wqs[0] + wqs[1] + wqs[2] + wqs[3];
        rsum[row] = s_sx * (float)t;
        rscale[row] = s_sx;
    }
}

// ---------------------------------------------------------------------------
// 256x256 int8 GEMM, ONE phase per K=64 slab (merged QM halves):
//   READ af[8]+bf[4] (12 ds_read_b128, slot s&3) | STAGE slab s+3 (A+B,
//   4 gloads, slot (s+3)&3) | lgkmcnt(0) | 32 MFMA | vmcnt(4) | barrier.
// Halves the barrier count vs the R10 8-phase kernel (measured fully
// pipe-serialized: MFMA 653 + LDSread 565 + write 130 ~= wall 1266/phase).
// LDS layout byte-identical to R5/R10 (ring-4 16 KiB units A, B at +64K;
// slot (s&3) == old (buf*2+ks)). Same swizzle, same staging addresses.
// Ledger (induction): phase s's VM4 proves slab s+2 (2-phase landing slack;
// enter with 4 outstanding, stage -> 8, wait <=4). Write-safety: stage into
// slot (s-1)&3 -- slab s-1's reads were lgkm(0)-proven before phase s-1's
// barrier, stage issued after it. Tail: clamped stages (s>=NS-3) land in
// slots never read again (s=61->slot0 last read ph60, 62->1@61, 63->2@62).
// Accumulation K-order unchanged -> bit-identical output to R10.
// out[m,o] = sc[o]*(sx[m]*dot_i32[m,o] - zp[o]*rsum[m]) + bias[o]
// ---------------------------------------------------------------------------
__device__ __forceinline__ void async16(void* lds, const void* g) {
    __builtin_amdgcn_global_load_lds(
        (const __attribute__((address_space(1))) unsigned*)g,
        (__attribute__((address_space(3))) unsigned*)lds, 16, 0, 0);
}

__global__ __launch_bounds__(512, 2) void qgemm1p(
    const char* __restrict__ A, const char* __restrict__ B,
    const float* __restrict__ rsum, const float* __restrict__ rscale,
    const float* __restrict__ scale, const float* __restrict__ zp,
    const float* __restrict__ bias, float* __restrict__ C,
    int M, int N, int K) {
    extern __shared__ char smem[];
    char* const AsB = smem;            // 4 x 16 KiB A ring slots
    char* const BsB = smem + 65536;    // 4 x 16 KiB B ring slots

    const int tid  = threadIdx.x;
    const int lane = tid & 63;
    const int wid  = tid >> 6;
    const int wm = wid >> 2, wn = wid & 3;   // 2 x 4 waves, wave tile 128x64
    const int l15 = lane & 15;

    // bijective XCD swizzle (gridDim.x % 8 == 0)
    const int nbn = N >> 8;
    int wg = blockIdx.x;
    wg = (wg & 7) * (gridDim.x >> 3) + (wg >> 3);
    const int bm = wg / nbn, bn = wg % nbn;

    // per-thread staging source offsets (inverse-swizzled global address)
    const int r0s = tid >> 2, sls = tid & 3;
    size_t a_src[2], b_src[2];
    int lds_off[2];
    #pragma unroll
    for (int j = 0; j < 2; ++j) {
        const int row = r0s + j * 128;
        const int sl  = sls ^ ((row >> 1) & 3);
        a_src[j] = ((size_t)(bm * 256 + row)) * K + sl * 16;
        b_src[j] = ((size_t)(bn * 256 + row)) * K + sl * 16;
        lds_off[j] = (j * 512 + tid) * 16;
    }

    // stage slab u (K-byte offset u*64) into ring slot sl: A + B, 4 gloads
    auto STAGE = [&](int u, int sl) {
        const int kc = u * 64;
        char* const da = AsB + sl * 16384;
        char* const db = BsB + sl * 16384;
        #pragma unroll
        for (int j = 0; j < 2; ++j) async16(da + lds_off[j], A + a_src[j] + kc);
        #pragma unroll
        for (int j = 0; j < 2; ++j) async16(db + lds_off[j], B + b_src[j] + kc);
    };

    // fragment-read constants (swizzled ds_read address)
    const int sw16 = (((lane >> 4) ^ ((lane >> 1) & 3)) << 4);
    const int a_ro = (wm * 128 + l15) * 64 + sw16;   // + mf*1024, mf 0..7
    const int b_ro = (wn * 64 + l15) * 64 + sw16;    // + nf*1024, nf 0..3

    i32x4 acc[8][4] = {};

    const int NS = K >> 6;     // 64 slabs

#define PHASE(S, SL)                                                           \
    {                                                                          \
        const char* _ha = AsB + (SL) * 16384;                                  \
        const char* _hb = BsB + (SL) * 16384;                                  \
        i32x4 af[8], bf[4];                                                    \
        _Pragma("unroll")                                                      \
        for (int m = 0; m < 8; ++m)                                            \
            af[m] = *(const i32x4*)(_ha + a_ro + m * 1024);                    \
        _Pragma("unroll")                                                      \
        for (int n = 0; n < 4; ++n)                                            \
            bf[n] = *(const i32x4*)(_hb + b_ro + n * 1024);                    \
        int _u = (S) + 3; if (_u >= NS) _u = NS - 1;                           \
        STAGE(_u, ((SL) + 3) & 3);                                             \
        asm volatile("s_waitcnt lgkmcnt(0)" ::: "memory");                     \
        __builtin_amdgcn_sched_barrier(0);                                     \
        __builtin_amdgcn_s_setprio(1);                                         \
        _Pragma("unroll")                                                      \
        for (int m = 0; m < 8; ++m)                                            \
            _Pragma("unroll")                                                  \
            for (int n = 0; n < 4; ++n)                                        \
                acc[m][n] = __builtin_amdgcn_mfma_i32_16x16x64_i8(             \
                    af[m], bf[n], acc[m][n], 0, 0, 0);                         \
        __builtin_amdgcn_s_setprio(0);                                         \
        __builtin_amdgcn_sched_barrier(0);                                     \
        asm volatile("s_waitcnt vmcnt(4)" ::: "memory");                       \
        asm volatile("s_barrier" ::: "memory");                                \
    }

    // ---- prologue: stage slabs 0,1,2; prove slab 0 (vmcnt 12 -> 8) ----
    STAGE(0, 0); STAGE(1, 1); STAGE(2, 2);
    asm volatile("s_waitcnt vmcnt(8)" ::: "memory");
    asm volatile("s_barrier" ::: "memory");

    #pragma unroll 1
    for (int i = 0; i < NS / 4; ++i) {
        const int s = 4 * i;
        PHASE(s + 0, 0)
        PHASE(s + 1, 1)
        PHASE(s + 2, 2)
        PHASE(s + 3, 3)
    }
#undef PHASE

    // ---- epilogue: dequant. D: col=lane&15, row=4*(lane>>4)+i ----
    float sc[4], zz[4], bb[4];
    #pragma unroll
    for (int n = 0; n < 4; ++n) {
        const int o = bn * 256 + wn * 64 + n * 16 + l15;
        sc[n] = scale[o]; zz[n] = zp[o]; bb[n] = bias[o];
    }
    const int hi4 = (lane >> 4) << 2;
    #pragma unroll
    for (int mf = 0; mf < 8; ++mf) {
        const int r0 = bm * 256 + wm * 128 + mf * 16 + hi4;
        float rs[4], sx[4];
        #pragma unroll
        for (int i = 0; i < 4; ++i) { rs[i] = rsum[r0 + i]; sx[i] = rscale[r0 + i]; }
        #pragma unroll
        for (int n = 0; n < 4; ++n) {
            const int o = bn * 256 + wn * 64 + n * 16 + l15;
            #pragma unroll
            for (int i = 0; i < 4; ++i)
                C[(size_t)(r0 + i) * N + o] =
                    sc[n] * (sx[i] * (float)acc[mf][n][i] - zz[n] * rs[i]) + bb[n];
        }
    }
}

// ---------------------------------------------------------------------------
extern "C" void kernel_launch(void* const* d_in, const int* in_sizes, int n_in,
                              void* d_out, int out_size, void* d_ws, size_t ws_size,
                              hipStream_t stream) {
    const float* x     = (const float*)d_in[0];
    const int*   w     = (const int*)d_in[1];
    const float* scale = (const float*)d_in[2];
    const float* zp    = (const float*)d_in[3];
    const float* bias  = (const float*)d_in[4];
    float* out = (float*)d_out;

    const int N = in_sizes[2];              // D_OUT = 4096
    const int K = in_sizes[1] / N;          // D_IN  = 4096
    const int M = in_sizes[0] / K;          // B*S   = 8192

    char*  xq  = (char*)d_ws;                                   // M*K bytes
    char*  wq  = (char*)d_ws + (size_t)M * K;                   // N*K bytes
    float* rs  = (float*)((char*)d_ws + (size_t)M * K + (size_t)N * K);
    float* rsc = rs + M;

    const int wblocks = (int)(((size_t)N * K / 16) / 256);      // 4096
    prep_fused<<<M + wblocks, 256, 0, stream>>>(x, w, (int*)xq, (int*)wq,
                                                rs, rsc, M, K);

    (void)hipFuncSetAttribute((const void*)qgemm1p,
                              hipFuncAttributeMaxDynamicSharedMemorySize, 131072);
    const int nwg = (M / 256) * (N / 256);   // 512, % 8 == 0
    qgemm1p<<<nwg, 512, 131072, stream>>>(xq, wq, rs, rsc, scale, zp, bias,
                                          out, M, N, K);
}